// Round 9
// baseline (112.676 us; speedup 1.0000x reference)
//
#include <hip/hip_runtime.h>
#include <math.h>

// Problem constants (fixed by the reference's setup_inputs)
#define T_STEPS 16
#define BB      128
#define VOCAB   32000
#define V4      (VOCAB / 4)   // 8000 float4 per row
#define BEAM    4
#define BATCH   (BB / BEAM)   // 32
#define NROWS   (T_STEPS * BB)        // 2048
#define TAU     3.0f          // survivor threshold: E[survivors/row] ~ 43
#define CAP_S   128           // per-row survivor capacity (12.9 sigma margin)
#define CHUNK_F4 2000         // float4 per stream block (4 blocks/row)

typedef float f32x4 __attribute__((ext_vector_type(4)));

// Non-temporal float4 load: emits global_load_dwordx4 with the 'nt' cache
// flag -> bypasses/early-evicts L3 allocation on the streaming read path.
__device__ __forceinline__ f32x4 ntload(const f32x4* p) {
    return __builtin_nontemporal_load(p);
}

// ---------------------------------------------------------------------------
// Total-order comparator matching jax.lax.top_k: value descending, index
// ascending on ties. (a ranks before b)?
__device__ __forceinline__ bool gtvi(float av, int ai, float bv, int bi) {
    return (av > bv) || (av == bv && ai < bi);
}

// Insert (x, gi) into a sorted-descending top-8 list held in registers.
__device__ __forceinline__ void ins8(float (&v)[8], int (&ix)[8], float x, int gi) {
    if (gtvi(x, gi, v[7], ix[7])) {
        v[7] = x; ix[7] = gi;
#pragma unroll
        for (int j = 7; j > 0; --j) {
            if (gtvi(v[j], ix[j], v[j - 1], ix[j - 1])) {
                float tv = v[j]; v[j] = v[j - 1]; v[j - 1] = tv;
                int   ti = ix[j]; ix[j] = ix[j - 1]; ix[j - 1] = ti;
            }
        }
    }
}

// Wave(64)-level butterfly merge of per-lane sorted-desc 8-lists.
__device__ __forceinline__ void wave_merge8(float (&v)[8], int (&ix)[8]) {
#pragma unroll
    for (int m = 1; m < 64; m <<= 1) {
        float u[8]; int ju[8];
#pragma unroll
        for (int k = 0; k < 8; ++k) {
            u[k]  = __shfl_xor(v[k],  m, 64);
            ju[k] = __shfl_xor(ix[k], m, 64);
        }
        float w[8]; int jw[8];
#pragma unroll
        for (int k = 0; k < 8; ++k) {
            if (gtvi(u[7 - k], ju[7 - k], v[k], ix[k])) { w[k] = u[7 - k]; jw[k] = ju[7 - k]; }
            else                                        { w[k] = v[k];     jw[k] = ix[k];     }
        }
#define CE_DESC(a, b)                                                         \
        if (gtvi(w[b], jw[b], w[a], jw[a])) {                                 \
            float tv = w[a]; w[a] = w[b]; w[b] = tv;                          \
            int   ti = jw[a]; jw[a] = jw[b]; jw[b] = ti;                      \
        }
        CE_DESC(0, 4) CE_DESC(1, 5) CE_DESC(2, 6) CE_DESC(3, 7)
        CE_DESC(0, 2) CE_DESC(1, 3) CE_DESC(4, 6) CE_DESC(5, 7)
        CE_DESC(0, 1) CE_DESC(2, 3) CE_DESC(4, 5) CE_DESC(6, 7)
#undef CE_DESC
#pragma unroll
        for (int k = 0; k < 8; ++k) { v[k] = w[k]; ix[k] = jw[k]; }
    }
}

// ---------------------------------------------------------------------------
// Kernel A: streaming pass. 4 blocks per row (8192 blocks x 256 threads).
// Per thread: 8 unconditional burst NON-TEMPORAL float4 loads, then exp-sum
// + rare threshold-survivor append to a global per-row list. Partial
// exp-sums go to sums4[row][chunk] (fixed combine order -> deterministic).
__global__ __launch_bounds__(256) void stream_scan(
    const float* __restrict__ logits,
    const int*   __restrict__ pad_p,
    const int*   __restrict__ unk_p,
    float* __restrict__ sv,     // [NROWS][CAP_S] survivor values
    int*   __restrict__ si,     // [NROWS][CAP_S] survivor words
    int*   __restrict__ cnt,    // [NROWS] survivor counts (pre-zeroed)
    float* __restrict__ sums4)  // [NROWS][4] partial exp-sums
{
    __shared__ float s_red[4];

    const int bid   = blockIdx.x;
    const int row   = bid >> 2;
    const int chunk = bid & 3;
    const int tid   = threadIdx.x;
    const int pad   = *pad_p, unk = *unk_p;
    const int rowb  = row * CAP_S;
    const int wchunk = chunk * CHUNK_F4;   // first float4 index of this chunk
    const f32x4* __restrict__ src =
        reinterpret_cast<const f32x4*>(logits + (size_t)row * VOCAB) + wchunk;

    // ---- 8 burst non-temporal loads, no branches in between ----
    // k=0..6 cover float4 0..1791 (all valid); k=7 covers 1792..1999
    // (valid iff tid<208; clamped duplicate load otherwise, excluded below).
    const bool v7 = (tid < 208);
    const int  i7 = 1792 + (v7 ? tid : 207);
    f32x4 r0 = ntload(src + tid);
    f32x4 r1 = ntload(src + tid + 256);
    f32x4 r2 = ntload(src + tid + 512);
    f32x4 r3 = ntload(src + tid + 768);
    f32x4 r4 = ntload(src + tid + 1024);
    f32x4 r5 = ntload(src + tid + 1280);
    f32x4 r6 = ntload(src + tid + 1536);
    f32x4 r7 = ntload(src + i7);

    float tsum = 0.0f;

    auto do4 = [&](f32x4 q, int wbase) {   // wbase = global word idx of q[0]
        tsum += (__expf(q[0]) + __expf(q[1])) + (__expf(q[2]) + __expf(q[3]));
        const float mx = fmaxf(fmaxf(q[0], q[1]), fmaxf(q[2], q[3]));
        if (__builtin_expect(mx > TAU, 0)) {
            const bool s0 = q[0] > TAU && (wbase + 0) != pad && (wbase + 0) != unk;
            const bool s1 = q[1] > TAU && (wbase + 1) != pad && (wbase + 1) != unk;
            const bool s2 = q[2] > TAU && (wbase + 2) != pad && (wbase + 2) != unk;
            const bool s3 = q[3] > TAU && (wbase + 3) != pad && (wbase + 3) != unk;
            const int c4 = (int)s0 + (int)s1 + (int)s2 + (int)s3;
            if (c4) {
                int p = atomicAdd(&cnt[row], c4);
                if (s0) { if (p < CAP_S) { sv[rowb + p] = q[0]; si[rowb + p] = wbase + 0; } ++p; }
                if (s1) { if (p < CAP_S) { sv[rowb + p] = q[1]; si[rowb + p] = wbase + 1; } ++p; }
                if (s2) { if (p < CAP_S) { sv[rowb + p] = q[2]; si[rowb + p] = wbase + 2; } ++p; }
                if (s3) { if (p < CAP_S) { sv[rowb + p] = q[3]; si[rowb + p] = wbase + 3; } ++p; }
            }
        }
    };

    const int wb0 = (wchunk + tid) * 4;    // word index of r0[0]
    do4(r0, wb0);
    do4(r1, wb0 + 1024);
    do4(r2, wb0 + 2048);
    do4(r3, wb0 + 3072);
    do4(r4, wb0 + 4096);
    do4(r5, wb0 + 5120);
    do4(r6, wb0 + 6144);
    if (v7) do4(r7, (wchunk + i7) * 4);

    // ---- block reduction of partial exp-sum -> sums4[row][chunk] ----
#pragma unroll
    for (int m = 1; m < 64; m <<= 1) tsum += __shfl_xor(tsum, m, 64);
    const int wv = tid >> 6, ln = tid & 63;
    if (ln == 0) s_red[wv] = tsum;
    __syncthreads();
    if (tid == 0)
        sums4[row * 4 + chunk] = (s_red[0] + s_red[1]) + (s_red[2] + s_red[3]);
}

// ---------------------------------------------------------------------------
// Kernel B: per-row selection. One wave per row. Exact top-8 of the survivor
// list (order-independent via total-order comparator), normalized by the
// deterministic fixed-order logS. Fallback: exact full-row rescan if the
// survivor list under/overflowed (never for N(0,1) rows).
__global__ __launch_bounds__(64) void select_topk(
    const float* __restrict__ logits,
    const int*   __restrict__ pad_p,
    const int*   __restrict__ unk_p,
    const float* __restrict__ sv,
    const int*   __restrict__ si,
    const int*   __restrict__ cnt,
    const float* __restrict__ sums4,
    float* __restrict__ topv,
    int*   __restrict__ topi)
{
    const int row  = blockIdx.x;
    const int lane = threadIdx.x;

    const float logS = logf(((sums4[row * 4 + 0] + sums4[row * 4 + 1]) +
                             (sums4[row * 4 + 2] + sums4[row * 4 + 3])));
    const int n = cnt[row];

    float v[8]; int ix[8];
#pragma unroll
    for (int k = 0; k < 8; ++k) { v[k] = -INFINITY; ix[k] = 0x7FFFFFFF; }

    if (n >= 8 && n <= CAP_S) {
        const int rowb = row * CAP_S;
        for (int c = lane; c < n; c += 64) ins8(v, ix, sv[rowb + c], si[rowb + c]);
    } else {
        // exact fallback: full-row scan (wave-parallel)
        const int pad = *pad_p, unk = *unk_p;
        const float4* __restrict__ src =
            reinterpret_cast<const float4*>(logits + (size_t)row * VOCAB);
        for (int kv = lane; kv < V4; kv += 64) {
            float4 q = src[kv];
            const int gi = kv * 4;
            if ((gi + 0) != pad && (gi + 0) != unk) ins8(v, ix, q.x, gi + 0);
            if ((gi + 1) != pad && (gi + 1) != unk) ins8(v, ix, q.y, gi + 1);
            if ((gi + 2) != pad && (gi + 2) != unk) ins8(v, ix, q.z, gi + 2);
            if ((gi + 3) != pad && (gi + 3) != unk) ins8(v, ix, q.w, gi + 3);
        }
    }

    wave_merge8(v, ix);
    if (lane == 0) {
        float* ov = topv + (size_t)row * 8;
        int*   oi = topi + (size_t)row * 8;
#pragma unroll
        for (int k = 0; k < 8; ++k) { ov[k] = v[k] - logS; oi[k] = ix[k]; }
    }
}

// ---------------------------------------------------------------------------
// Phase 2: 16-step beam scan, one wave per batch, fully wave-parallel.
// All candidates preloaded to LDS once; per step a 64-lane bitonic sort by
// (val desc, cand-idx asc) gives the exact top-8, then an 8-lane mini-sort
// after eos masking gives the exact top_k(masked, 4).
__global__ __launch_bounds__(64) void phase2_beam_scan(
    const float* __restrict__ topv,
    const int*   __restrict__ topi,
    const int*   __restrict__ eos_p,
    float* __restrict__ out)
{
    const int b    = blockIdx.x;   // batch index
    const int lane = threadIdx.x;  // 0..63, single wave
    const int eos  = *eos_p;

    __shared__ float s_v[T_STEPS][32];
    __shared__ int   s_w[T_STEPS][32];
    __shared__ float s_sc[BEAM];
    __shared__ int   s_rb[T_STEPS][BEAM];
    __shared__ int   s_rw[T_STEPS][BEAM];

    for (int g = lane; g < T_STEPS * 32; g += 64) {
        const int t = g >> 5, j = g & 31;
        const size_t off = (size_t)t * (BB * 8) + (size_t)b * (BEAM * 8) + j;
        s_v[t][j] = topv[off];
        s_w[t][j] = topi[off];
    }
    if (lane < BEAM) s_sc[lane] = 0.0f;
    __syncthreads();

    for (int t = 0; t < T_STEPS; ++t) {
        float val; int word, cj;
        if (lane < 32) {
            cj   = lane;                       // beam*8 + pos
            word = s_w[t][lane];
            val  = s_v[t][lane] + s_sc[lane >> 3];
        } else {
            cj = 64 + lane; word = 0; val = -INFINITY;
        }

        // ---- 64-lane bitonic sort, descending by (val, cj asc) ----
#pragma unroll
        for (int k = 2; k <= 64; k <<= 1) {
#pragma unroll
            for (int j = k >> 1; j > 0; j >>= 1) {
                const float ov = __shfl_xor(val,  j, 64);
                const int   oc = __shfl_xor(cj,   j, 64);
                const int   ow = __shfl_xor(word, j, 64);
                const bool dirDesc   = ((lane & k) == 0);
                const bool iAmLow    = ((lane & j) == 0);
                const bool mineFirst = gtvi(val, cj, ov, oc);
                const bool takeOther = dirDesc ? (iAmLow ? !mineFirst : mineFirst)
                                               : (iAmLow ? mineFirst : !mineFirst);
                if (takeOther) { val = ov; cj = oc; word = ow; }
            }
        }

        // ---- lanes 0..7 = top-8 desc. eos mask, then exact top_k(masked,4)
        float mval; int pos = lane, srcb = 0, w8 = 0;
        if (lane < 8) {
            w8   = word;
            srcb = cj >> 3;
            const bool iseos = (w8 == eos) && (val > -INFINITY);
            mval = iseos ? -INFINITY : val;
        } else {
            mval = -INFINITY;
        }
#pragma unroll
        for (int k = 2; k <= 8; k <<= 1) {
#pragma unroll
            for (int j = k >> 1; j > 0; j >>= 1) {
                const float ov = __shfl_xor(mval, j, 64);
                const int   op = __shfl_xor(pos,  j, 64);
                const int   ob = __shfl_xor(srcb, j, 64);
                const int   ow = __shfl_xor(w8,   j, 64);
                const bool dirDesc   = ((lane & k) == 0);
                const bool iAmLow    = ((lane & j) == 0);
                const bool mineFirst = gtvi(mval, pos, ov, op);
                const bool takeOther = dirDesc ? (iAmLow ? !mineFirst : mineFirst)
                                               : (iAmLow ? mineFirst : !mineFirst);
                if (takeOther) { mval = ov; pos = op; srcb = ob; w8 = ow; }
            }
        }

        if (lane < 4) {
            s_sc[lane]    = mval;   // new cumulative scores (sel_scores)
            s_rb[t][lane] = srcb;   // source (old) beam
            s_rw[t][lane] = w8;     // chosen word
        }
        __syncthreads();
    }

    // Backtrace + output (d_out = [scores (128) | tokens (128*17)], f32)
    if (lane < BEAM) {
        out[b * BEAM + lane] = s_sc[lane];
        float* tout = out + BATCH * BEAM + (size_t)(b * BEAM + lane) * (T_STEPS + 1);
        int bp = lane;
#pragma unroll
        for (int t = T_STEPS - 1; t >= 0; --t) {
            tout[t + 1] = (float)s_rw[t][bp];
            bp = s_rb[t][bp];
        }
        tout[0] = (float)eos;   // begin token
    }
}

// ---------------------------------------------------------------------------
extern "C" void kernel_launch(void* const* d_in, const int* in_sizes, int n_in,
                              void* d_out, int out_size, void* d_ws, size_t ws_size,
                              hipStream_t stream) {
    const float* logits = (const float*)d_in[0];
    const int*   pad_p  = (const int*)d_in[1];
    const int*   unk_p  = (const int*)d_in[2];
    const int*   eos_p  = (const int*)d_in[3];
    // d_in[4] = beam_size (hardcoded 4 to match shapes)

    // Workspace layout (bytes):
    //   sv    [NROWS*CAP_S] f32   @ 0            (1,048,576)
    //   si    [NROWS*CAP_S] i32   @ 1,048,576    (1,048,576)
    //   cnt   [NROWS]       i32   @ 2,097,152    (8,192)   <- zeroed each call
    //   sums4 [NROWS*4]     f32   @ 2,105,344    (32,768)
    //   topv  [NROWS*8]     f32   @ 2,138,112    (65,536)
    //   topi  [NROWS*8]     i32   @ 2,203,648    (65,536)
    char* ws = (char*)d_ws;
    float* sv    = (float*)(ws + 0);
    int*   si    = (int*)  (ws + 1048576);
    int*   cnt   = (int*)  (ws + 2097152);
    float* sums4 = (float*)(ws + 2105344);
    float* topv  = (float*)(ws + 2138112);
    int*   topi  = (int*)  (ws + 2203648);

    hipMemsetAsync(cnt, 0, NROWS * sizeof(int), stream);

    hipLaunchKernelGGL(stream_scan, dim3(NROWS * 4), dim3(256), 0, stream,
                       logits, pad_p, unk_p, sv, si, cnt, sums4);
    hipLaunchKernelGGL(select_topk, dim3(NROWS), dim3(64), 0, stream,
                       logits, pad_p, unk_p, sv, si, cnt, sums4, topv, topi);
    hipLaunchKernelGGL(phase2_beam_scan, dim3(BATCH), dim3(64), 0, stream,
                       topv, topi, eos_p, (float*)d_out);
}